// Round 4
// baseline (530.249 us; speedup 1.0000x reference)
//
#include <hip/hip_runtime.h>
#include <hip/hip_bf16.h>

// S2Conv: x (512,64,121) f32, w (64,64,512) f32, Y (512,121) f32
// out (512,64,1771) f32.
// psi[e,g,i] = sum_n Y[n,i] w[e,g,n] / sqrt(512)
// out[b,g, OFF_l + u*d + m] = (1/8) sum_e psi[e,g,l^2+u] * x[b,e,l^2+m]
//
// Round 4: ATTRIBUTION ROUND. Kernels byte-identical to round 3; conv_kernel
// is launched 3x (idempotent: pure function of psi_t/x_t, no atomics).
// T_conv = (dur_r4 - dur_r3)/2. This resolves where the ~120us of
// unattributed time lives before any further optimization.

#define OUTROW 1771
#define OUTB   113344  // 64*1771

typedef __attribute__((ext_vector_type(8))) short bf16x8;
typedef __attribute__((ext_vector_type(4))) float floatx4;

// cumulative conv block counts per l (NGT*NBT): {2,28,66,120,190,299,432,496,770,880,946}
__device__ __constant__ int c_blk[12] = {0,2,30,96,216,406,705,1137,1633,2403,3283,4229};
__device__ __constant__ signed char c_ltab[121] = {
  0,
  1,1,1,
  2,2,2,2,2,
  3,3,3,3,3,3,3,
  4,4,4,4,4,4,4,4,4,
  5,5,5,5,5,5,5,5,5,5,5,
  6,6,6,6,6,6,6,6,6,6,6,6,6,
  7,7,7,7,7,7,7,7,7,7,7,7,7,7,7,
  8,8,8,8,8,8,8,8,8,8,8,8,8,8,8,8,8,
  9,9,9,9,9,9,9,9,9,9,9,9,9,9,9,9,9,9,9,
  10,10,10,10,10,10,10,10,10,10,10,10,10,10,10,10,10,10,10,10,10
};

// ---------------------------------------------------------------------------
// Prep (unchanged): blocks [0,64): psi via MFMA, one block per g.
//                   blocks [64,576): x_t transpose, one block per b.
// psi_t[64*l^2 + g*d + u][e] = scale * sum_n w[e,g,n]*Y[n,l^2+u]   (bf16)
// x_t [512*l^2 + b*d + m][e] = x[b,e,l^2+m]                        (bf16)
// ---------------------------------------------------------------------------
__global__ __launch_bounds__(256) void prep_kernel(
    const float* __restrict__ x, const float* __restrict__ w,
    const float* __restrict__ Y,
    __hip_bfloat16* __restrict__ psi_t, __hip_bfloat16* __restrict__ x_t)
{
  __shared__ float smem[8256];
  const int t = threadIdx.x;

  if (blockIdx.x < 64) {
    const int g    = blockIdx.x;
    const int wv   = t >> 6, lane = t & 63;
    const int ln15 = lane & 15, quad = lane >> 4;

    floatx4 acc[2][4] = {};   // [i-tile][e-tile], statically indexed

    for (int n0 = 0; n0 < 512; n0 += 64) {
      __syncthreads();
      {
        const float4* src = (const float4*)(Y + n0*121);
        float4* dst = (float4*)smem;
        for (int idx = t; idx < 1936; idx += 256) dst[idx] = src[idx];
      }
      __syncthreads();

      #pragma unroll
      for (int ks = 0; ks < 2; ++ks) {
        const int kb = ks*32 + quad*8;

        bf16x8 ahi[2], alo[2];
        #pragma unroll
        for (int ti = 0; ti < 2; ++ti) {
          const int irow = (wv << 5) + (ti << 4) + ln15;
          #pragma unroll
          for (int j = 0; j < 8; ++j) {
            float v = smem[(kb + j)*121 + irow];
            __hip_bfloat16 h = __float2bfloat16(v);
            float hf = __bfloat162float(h);
            __hip_bfloat16 lo = __float2bfloat16(v - hf);
            ahi[ti][j] = *(short*)&h;
            alo[ti][j] = *(short*)&lo;
          }
        }

        bf16x8 bhi[4], blo[4];
        #pragma unroll
        for (int te = 0; te < 4; ++te) {
          const int e = (te << 4) + ln15;
          const float* wp = w + ((e << 6) + g)*512 + n0 + kb;
          float4 wa = *(const float4*)wp;
          float4 wb = *(const float4*)(wp + 4);
          float v[8] = {wa.x, wa.y, wa.z, wa.w, wb.x, wb.y, wb.z, wb.w};
          #pragma unroll
          for (int j = 0; j < 8; ++j) {
            __hip_bfloat16 h = __float2bfloat16(v[j]);
            float hf = __bfloat162float(h);
            __hip_bfloat16 lo = __float2bfloat16(v[j] - hf);
            bhi[te][j] = *(short*)&h;
            blo[te][j] = *(short*)&lo;
          }
        }

        #pragma unroll
        for (int ti = 0; ti < 2; ++ti) {
          #pragma unroll
          for (int te = 0; te < 4; ++te) {
            acc[ti][te] = __builtin_amdgcn_mfma_f32_16x16x32_bf16(ahi[ti], bhi[te], acc[ti][te], 0, 0, 0);
            acc[ti][te] = __builtin_amdgcn_mfma_f32_16x16x32_bf16(ahi[ti], blo[te], acc[ti][te], 0, 0, 0);
            acc[ti][te] = __builtin_amdgcn_mfma_f32_16x16x32_bf16(alo[ti], bhi[te], acc[ti][te], 0, 0, 0);
          }
        }
      }
    }

    const float scale = 0.00552427172801990267f;  // 1/(8*sqrt(512))
    #pragma unroll
    for (int ti = 0; ti < 2; ++ti) {
      #pragma unroll
      for (int rr = 0; rr < 4; ++rr) {
        const int i = (wv << 5) + (ti << 4) + (quad << 2) + rr;
        if (i < 121) {
          int l = c_ltab[i];
          int d = 2*l + 1;
          int row = 64*l*l + g*d + (i - l*l);
          #pragma unroll
          for (int te = 0; te < 4; ++te) {
            __hip_bfloat16 hv = __float2bfloat16(acc[ti][te][rr] * scale);
            psi_t[row*64 + (te << 4) + ln15] = hv;
          }
        }
      }
    }
  } else {
    const int b = blockIdx.x - 64;
    {
      const float4* src = (const float4*)(x + b*7744);
      float4* dst = (float4*)smem;
      for (int idx = t; idx < 1936; idx += 256) dst[idx] = src[idx];
    }
    __syncthreads();
    const int wv = t >> 6, lane = t & 63;
    for (int ii = wv; ii < 121; ii += 4) {
      int l = c_ltab[ii];
      int d = 2*l + 1;
      int row = 512*l*l + b*d + (ii - l*l);
      x_t[row*64 + lane] = __float2bfloat16(smem[lane*121 + ii]);
    }
  }
}

// ---------------------------------------------------------------------------
// Conv (unchanged from round 3): per-l GEMM, (g,b)-aligned tiles, 512-thread
// blocks (8 waves), 64x256 tile, LDS [64][258] f32, contiguous d^2 epilogue.
// ---------------------------------------------------------------------------
#define LPITCH 258   // row stride (f32 words); uniform <=2-way LDS (free)

template <int L>
__device__ void conv_body(int r, int t,
                          const ushort* __restrict__ psi,
                          const ushort* __restrict__ xt,
                          float* __restrict__ out, float* lt)
{
  constexpr int d    = 2*L + 1;
  constexpr int dd   = d*d;
  constexpr int GT   = 64  / d;            // whole g's per block
  constexpr int BT   = 256 / d;            // whole b's per block
  constexpr int NBT  = (512 + BT - 1) / BT;
  constexpr int OFFL = L*(2*L - 1)*(2*L + 1)/3;   // sum_{k<L} (2k+1)^2

  const int wv = t >> 6, lane = t & 63;
  const int wslot = wv & 3, qhalf = wv >> 2;
  const int ln15 = lane & 15, quad = lane >> 4;

  const int gtI = r / NBT;                 // compile-time magic div
  const int btI = r - gtI*NBT;
  const int g0 = gtI*GT, b0 = btI*BT;

  // ---- MFMA phase: 64 p-rows x 256 q-cols, K=64; this wave: 16p x 128q ----
  int pr = g0*d + wslot*16 + ln15;
  if (pr > 64*d - 1) pr = 64*d - 1;        // edge clamp (garbage masked in epilogue)
  const ushort* psiRow = psi + (64*L*L + pr)*64 + quad*8;
  const bf16x8 af0 = *(const bf16x8*)(psiRow);
  const bf16x8 af1 = *(const bf16x8*)(psiRow + 32);

  const ushort* xbase = xt + 512*L*L*64 + quad*8;

  #pragma unroll 4
  for (int qi = 0; qi < 8; ++qi) {
    const int qq = qhalf*8 + qi;
    int qr = b0*d + qq*16 + ln15;
    if (qr > 512*d - 1) qr = 512*d - 1;
    const ushort* xr = xbase + qr*64;
    bf16x8 bf0 = *(const bf16x8*)(xr);
    bf16x8 bf1 = *(const bf16x8*)(xr + 32);
    floatx4 acc = {0.f, 0.f, 0.f, 0.f};
    acc = __builtin_amdgcn_mfma_f32_16x16x32_bf16(af0, bf0, acc, 0, 0, 0);
    acc = __builtin_amdgcn_mfma_f32_16x16x32_bf16(af1, bf1, acc, 0, 0, 0);
    // D layout: col = ln15 (q), row = quad*4+rr (p)
    float* dst = lt + (wslot*16 + quad*4)*LPITCH + qq*16 + ln15;
    #pragma unroll
    for (int rr = 0; rr < 4; ++rr) dst[rr*LPITCH] = acc[rr];
  }
  __syncthreads();

  // ---- Epilogue: complete d^2 runs per (b,g), contiguous stores; 8 waves ----
  if constexpr (dd >= 64) {
    for (int pp = wv; pp < GT*BT; pp += 8) {
      const int g_i = pp / BT;             // wave-uniform scalar div
      const int b_i = pp - g_i*BT;
      const int g = g0 + g_i, b = b0 + b_i;
      if (g >= 64 || b >= 512) continue;
      const int obase = b*OUTB + g*OUTROW + OFFL;
      const float* lrow = lt + (g_i*d)*LPITCH + b_i*d;
      #pragma unroll
      for (int o0 = 0; o0 < dd; o0 += 64) {
        int o = o0 + lane;
        if (o < dd) {
          int u = o / d;                   // compile-time magic
          int m = o - u*d;
          out[obase + o] = lrow[u*LPITCH + m];
        }
      }
    }
  } else {
    constexpr int PPI = 64 / dd;
    const int pq = lane / dd;              // compile-time magic
    const int o  = lane - pq*dd;
    const int u  = o / d;
    const int m  = o - u*d;
    for (int base = wv*PPI; base < GT*BT; base += 8*PPI) {
      int pp = base + pq;
      if (pq < PPI && pp < GT*BT) {
        int g_i = pp / BT;
        int b_i = pp - g_i*BT;
        int g = g0 + g_i, b = b0 + b_i;
        if (g < 64 && b < 512)
          out[b*OUTB + g*OUTROW + OFFL + o] = lt[(g_i*d + u)*LPITCH + b_i*d + m];
      }
    }
  }
}

__global__ __launch_bounds__(512) void conv_kernel(
    const __hip_bfloat16* __restrict__ psi_t,
    const __hip_bfloat16* __restrict__ x_t,
    float* __restrict__ out)
{
  __shared__ float lt[64*LPITCH];          // 66 KB -> 2 blocks x 512 thr = 16 waves/CU

  // bijective XCD swizzle (NWG=4229 = 8*528+5): each XCD gets a contiguous range
  const int orig = blockIdx.x;
  const int xcd = orig & 7, idx = orig >> 3;
  const int bid = (xcd < 5 ? xcd*529 : 2645 + (xcd - 5)*528) + idx;

  int l = 0;
  #pragma unroll
  for (int ll = 1; ll <= 10; ++ll)
    if (bid >= c_blk[ll]) l = ll;
  const int r = bid - c_blk[l];

  const ushort* psi = (const ushort*)psi_t;
  const ushort* xt  = (const ushort*)x_t;
  const int t = threadIdx.x;

  switch (l) {
    case 0:  conv_body<0 >(r, t, psi, xt, out, lt); break;
    case 1:  conv_body<1 >(r, t, psi, xt, out, lt); break;
    case 2:  conv_body<2 >(r, t, psi, xt, out, lt); break;
    case 3:  conv_body<3 >(r, t, psi, xt, out, lt); break;
    case 4:  conv_body<4 >(r, t, psi, xt, out, lt); break;
    case 5:  conv_body<5 >(r, t, psi, xt, out, lt); break;
    case 6:  conv_body<6 >(r, t, psi, xt, out, lt); break;
    case 7:  conv_body<7 >(r, t, psi, xt, out, lt); break;
    case 8:  conv_body<8 >(r, t, psi, xt, out, lt); break;
    case 9:  conv_body<9 >(r, t, psi, xt, out, lt); break;
    default: conv_body<10>(r, t, psi, xt, out, lt); break;
  }
}

extern "C" void kernel_launch(void* const* d_in, const int* in_sizes, int n_in,
                              void* d_out, int out_size, void* d_ws, size_t ws_size,
                              hipStream_t stream) {
  const float* x = (const float*)d_in[0];   // 512*64*121
  const float* w = (const float*)d_in[1];   // 64*64*512
  const float* Y = (const float*)d_in[2];   // 512*121
  float* out = (float*)d_out;               // 512*64*1771

  __hip_bfloat16* psi_t = (__hip_bfloat16*)d_ws;                       // 7744*64 bf16 (<1MB)
  __hip_bfloat16* x_t   = (__hip_bfloat16*)((char*)d_ws + (1 << 20));  // 61952*64 bf16 (~7.9MB)

  prep_kernel<<<576, 256, 0, stream>>>(x, w, Y, psi_t, x_t);
  // ATTRIBUTION: conv launched 3x (idempotent). T_conv = (dur_r4 - dur_r3)/2.
  conv_kernel<<<4229, 512, 0, stream>>>(psi_t, x_t, out);
  conv_kernel<<<4229, 512, 0, stream>>>(psi_t, x_t, out);
  conv_kernel<<<4229, 512, 0, stream>>>(psi_t, x_t, out);
}

// Round 5
// 510.786 us; speedup vs baseline: 1.0381x; 1.0381x over previous
//
#include <hip/hip_runtime.h>
#include <hip/hip_bf16.h>

// S2Conv: x (512,64,121) f32, w (64,64,512) f32, Y (512,121) f32
// out (512,64,1771) f32.
// psi[e,g,i] = sum_n Y[n,i] w[e,g,n] / sqrt(512)
// out[b,g, OFF_l + u*d + m] = (1/8) sum_e psi[e,g,l^2+u] * x[b,e,l^2+m]
//
// Round 5: STORE-ABLATION ROUND. Base = round 3 exactly (prep + 1 real conv,
// T_base=358). Plus 2 launches of conv<STORE=false>: identical loads, MFMA,
// LDS traffic, epilogue LDS reads — but global stores replaced by an asm
// value sink (no memory writes -> safe). T_nostore = (dur_r5 - 358)/2.
// Pre-committed: T_ns small -> conv is store-side-bound; T_ns ~= T_conv ->
// load/latency-bound.

#define OUTROW 1771
#define OUTB   113344  // 64*1771

typedef __attribute__((ext_vector_type(8))) short bf16x8;
typedef __attribute__((ext_vector_type(4))) float floatx4;

// cumulative conv block counts per l (NGT*NBT)
__device__ __constant__ int c_blk[12] = {0,2,30,96,216,406,705,1137,1633,2403,3283,4229};
__device__ __constant__ signed char c_ltab[121] = {
  0,
  1,1,1,
  2,2,2,2,2,
  3,3,3,3,3,3,3,
  4,4,4,4,4,4,4,4,4,
  5,5,5,5,5,5,5,5,5,5,5,
  6,6,6,6,6,6,6,6,6,6,6,6,6,
  7,7,7,7,7,7,7,7,7,7,7,7,7,7,7,
  8,8,8,8,8,8,8,8,8,8,8,8,8,8,8,8,8,
  9,9,9,9,9,9,9,9,9,9,9,9,9,9,9,9,9,9,9,
  10,10,10,10,10,10,10,10,10,10,10,10,10,10,10,10,10,10,10,10,10
};

// ---------------------------------------------------------------------------
// Prep (unchanged): blocks [0,64): psi via MFMA, one block per g.
//                   blocks [64,576): x_t transpose, one block per b.
// ---------------------------------------------------------------------------
__global__ __launch_bounds__(256) void prep_kernel(
    const float* __restrict__ x, const float* __restrict__ w,
    const float* __restrict__ Y,
    __hip_bfloat16* __restrict__ psi_t, __hip_bfloat16* __restrict__ x_t)
{
  __shared__ float smem[8256];
  const int t = threadIdx.x;

  if (blockIdx.x < 64) {
    const int g    = blockIdx.x;
    const int wv   = t >> 6, lane = t & 63;
    const int ln15 = lane & 15, quad = lane >> 4;

    floatx4 acc[2][4] = {};   // [i-tile][e-tile], statically indexed

    for (int n0 = 0; n0 < 512; n0 += 64) {
      __syncthreads();
      {
        const float4* src = (const float4*)(Y + n0*121);
        float4* dst = (float4*)smem;
        for (int idx = t; idx < 1936; idx += 256) dst[idx] = src[idx];
      }
      __syncthreads();

      #pragma unroll
      for (int ks = 0; ks < 2; ++ks) {
        const int kb = ks*32 + quad*8;

        bf16x8 ahi[2], alo[2];
        #pragma unroll
        for (int ti = 0; ti < 2; ++ti) {
          const int irow = (wv << 5) + (ti << 4) + ln15;
          #pragma unroll
          for (int j = 0; j < 8; ++j) {
            float v = smem[(kb + j)*121 + irow];
            __hip_bfloat16 h = __float2bfloat16(v);
            float hf = __bfloat162float(h);
            __hip_bfloat16 lo = __float2bfloat16(v - hf);
            ahi[ti][j] = *(short*)&h;
            alo[ti][j] = *(short*)&lo;
          }
        }

        bf16x8 bhi[4], blo[4];
        #pragma unroll
        for (int te = 0; te < 4; ++te) {
          const int e = (te << 4) + ln15;
          const float* wp = w + ((e << 6) + g)*512 + n0 + kb;
          float4 wa = *(const float4*)wp;
          float4 wb = *(const float4*)(wp + 4);
          float v[8] = {wa.x, wa.y, wa.z, wa.w, wb.x, wb.y, wb.z, wb.w};
          #pragma unroll
          for (int j = 0; j < 8; ++j) {
            __hip_bfloat16 h = __float2bfloat16(v[j]);
            float hf = __bfloat162float(h);
            __hip_bfloat16 lo = __float2bfloat16(v[j] - hf);
            bhi[te][j] = *(short*)&h;
            blo[te][j] = *(short*)&lo;
          }
        }

        #pragma unroll
        for (int ti = 0; ti < 2; ++ti) {
          #pragma unroll
          for (int te = 0; te < 4; ++te) {
            acc[ti][te] = __builtin_amdgcn_mfma_f32_16x16x32_bf16(ahi[ti], bhi[te], acc[ti][te], 0, 0, 0);
            acc[ti][te] = __builtin_amdgcn_mfma_f32_16x16x32_bf16(ahi[ti], blo[te], acc[ti][te], 0, 0, 0);
            acc[ti][te] = __builtin_amdgcn_mfma_f32_16x16x32_bf16(alo[ti], bhi[te], acc[ti][te], 0, 0, 0);
          }
        }
      }
    }

    const float scale = 0.00552427172801990267f;  // 1/(8*sqrt(512))
    #pragma unroll
    for (int ti = 0; ti < 2; ++ti) {
      #pragma unroll
      for (int rr = 0; rr < 4; ++rr) {
        const int i = (wv << 5) + (ti << 4) + (quad << 2) + rr;
        if (i < 121) {
          int l = c_ltab[i];
          int d = 2*l + 1;
          int row = 64*l*l + g*d + (i - l*l);
          #pragma unroll
          for (int te = 0; te < 4; ++te) {
            __hip_bfloat16 hv = __float2bfloat16(acc[ti][te][rr] * scale);
            psi_t[row*64 + (te << 4) + ln15] = hv;
          }
        }
      }
    }
  } else {
    const int b = blockIdx.x - 64;
    {
      const float4* src = (const float4*)(x + b*7744);
      float4* dst = (float4*)smem;
      for (int idx = t; idx < 1936; idx += 256) dst[idx] = src[idx];
    }
    __syncthreads();
    const int wv = t >> 6, lane = t & 63;
    for (int ii = wv; ii < 121; ii += 4) {
      int l = c_ltab[ii];
      int d = 2*l + 1;
      int row = 512*l*l + b*d + (ii - l*l);
      x_t[row*64 + lane] = __float2bfloat16(smem[lane*121 + ii]);
    }
  }
}

// ---------------------------------------------------------------------------
// Conv (structure identical to round 3), templated on STORE for ablation.
// ---------------------------------------------------------------------------
#define LPITCH 258   // row stride (f32 words); uniform <=2-way LDS (free)

template <int L, bool STORE>
__device__ void conv_body(int r, int t,
                          const ushort* __restrict__ psi,
                          const ushort* __restrict__ xt,
                          float* __restrict__ out, float* lt)
{
  constexpr int d    = 2*L + 1;
  constexpr int dd   = d*d;
  constexpr int GT   = 64  / d;            // whole g's per block
  constexpr int BT   = 256 / d;            // whole b's per block
  constexpr int NBT  = (512 + BT - 1) / BT;
  constexpr int OFFL = L*(2*L - 1)*(2*L + 1)/3;   // sum_{k<L} (2k+1)^2

  const int wv = t >> 6, lane = t & 63;
  const int wslot = wv & 3, qhalf = wv >> 2;
  const int ln15 = lane & 15, quad = lane >> 4;

  const int gtI = r / NBT;                 // compile-time magic div
  const int btI = r - gtI*NBT;
  const int g0 = gtI*GT, b0 = btI*BT;

  // ---- MFMA phase: 64 p-rows x 256 q-cols, K=64; this wave: 16p x 128q ----
  int pr = g0*d + wslot*16 + ln15;
  if (pr > 64*d - 1) pr = 64*d - 1;        // edge clamp (garbage masked in epilogue)
  const ushort* psiRow = psi + (64*L*L + pr)*64 + quad*8;
  const bf16x8 af0 = *(const bf16x8*)(psiRow);
  const bf16x8 af1 = *(const bf16x8*)(psiRow + 32);

  const ushort* xbase = xt + 512*L*L*64 + quad*8;

  #pragma unroll 4
  for (int qi = 0; qi < 8; ++qi) {
    const int qq = qhalf*8 + qi;
    int qr = b0*d + qq*16 + ln15;
    if (qr > 512*d - 1) qr = 512*d - 1;
    const ushort* xr = xbase + qr*64;
    bf16x8 bf0 = *(const bf16x8*)(xr);
    bf16x8 bf1 = *(const bf16x8*)(xr + 32);
    floatx4 acc = {0.f, 0.f, 0.f, 0.f};
    acc = __builtin_amdgcn_mfma_f32_16x16x32_bf16(af0, bf0, acc, 0, 0, 0);
    acc = __builtin_amdgcn_mfma_f32_16x16x32_bf16(af1, bf1, acc, 0, 0, 0);
    // D layout: col = ln15 (q), row = quad*4+rr (p)
    float* dst = lt + (wslot*16 + quad*4)*LPITCH + qq*16 + ln15;
    #pragma unroll
    for (int rr = 0; rr < 4; ++rr) dst[rr*LPITCH] = acc[rr];
  }
  __syncthreads();

  // ---- Epilogue: complete d^2 runs per (b,g); stores ablatable ----
  if constexpr (dd >= 64) {
    for (int pp = wv; pp < GT*BT; pp += 8) {
      const int g_i = pp / BT;             // wave-uniform scalar div
      const int b_i = pp - g_i*BT;
      const int g = g0 + g_i, b = b0 + b_i;
      if (g >= 64 || b >= 512) continue;
      const int obase = b*OUTB + g*OUTROW + OFFL;
      const float* lrow = lt + (g_i*d)*LPITCH + b_i*d;
      #pragma unroll
      for (int o0 = 0; o0 < dd; o0 += 64) {
        int o = o0 + lane;
        if (o < dd) {
          int u = o / d;                   // compile-time magic
          int m = o - u*d;
          float v = lrow[u*LPITCH + m];
          if constexpr (STORE) out[obase + o] = v;
          else asm volatile("" :: "v"(v));   // keep load+addr live, no write
        }
      }
    }
  } else {
    constexpr int PPI = 64 / dd;
    const int pq = lane / dd;              // compile-time magic
    const int o  = lane - pq*dd;
    const int u  = o / d;
    const int m  = o - u*d;
    for (int base = wv*PPI; base < GT*BT; base += 8*PPI) {
      int pp = base + pq;
      if (pq < PPI && pp < GT*BT) {
        int g_i = pp / BT;
        int b_i = pp - g_i*BT;
        int g = g0 + g_i, b = b0 + b_i;
        if (g < 64 && b < 512) {
          float v = lt[(g_i*d + u)*LPITCH + b_i*d + m];
          if constexpr (STORE) out[b*OUTB + g*OUTROW + OFFL + o] = v;
          else asm volatile("" :: "v"(v));
        }
      }
    }
  }
}

template <bool STORE>
__device__ void conv_top(const __hip_bfloat16* psi_t, const __hip_bfloat16* x_t,
                         float* out, float* lt)
{
  // bijective XCD swizzle (NWG=4229 = 8*528+5)
  const int orig = blockIdx.x;
  const int xcd = orig & 7, idx = orig >> 3;
  const int bid = (xcd < 5 ? xcd*529 : 2645 + (xcd - 5)*528) + idx;

  int l = 0;
  #pragma unroll
  for (int ll = 1; ll <= 10; ++ll)
    if (bid >= c_blk[ll]) l = ll;
  const int r = bid - c_blk[l];

  const ushort* psi = (const ushort*)psi_t;
  const ushort* xt  = (const ushort*)x_t;
  const int t = threadIdx.x;

  switch (l) {
    case 0:  conv_body<0 , STORE>(r, t, psi, xt, out, lt); break;
    case 1:  conv_body<1 , STORE>(r, t, psi, xt, out, lt); break;
    case 2:  conv_body<2 , STORE>(r, t, psi, xt, out, lt); break;
    case 3:  conv_body<3 , STORE>(r, t, psi, xt, out, lt); break;
    case 4:  conv_body<4 , STORE>(r, t, psi, xt, out, lt); break;
    case 5:  conv_body<5 , STORE>(r, t, psi, xt, out, lt); break;
    case 6:  conv_body<6 , STORE>(r, t, psi, xt, out, lt); break;
    case 7:  conv_body<7 , STORE>(r, t, psi, xt, out, lt); break;
    case 8:  conv_body<8 , STORE>(r, t, psi, xt, out, lt); break;
    case 9:  conv_body<9 , STORE>(r, t, psi, xt, out, lt); break;
    default: conv_body<10, STORE>(r, t, psi, xt, out, lt); break;
  }
}

__global__ __launch_bounds__(512) void conv_kernel_st(
    const __hip_bfloat16* __restrict__ psi_t,
    const __hip_bfloat16* __restrict__ x_t,
    float* __restrict__ out)
{
  __shared__ float lt[64*LPITCH];          // 66 KB
  conv_top<true>(psi_t, x_t, out, lt);
}

__global__ __launch_bounds__(512) void conv_kernel_ns(
    const __hip_bfloat16* __restrict__ psi_t,
    const __hip_bfloat16* __restrict__ x_t,
    float* __restrict__ out)
{
  __shared__ float lt[64*LPITCH];
  conv_top<false>(psi_t, x_t, out, lt);
}

extern "C" void kernel_launch(void* const* d_in, const int* in_sizes, int n_in,
                              void* d_out, int out_size, void* d_ws, size_t ws_size,
                              hipStream_t stream) {
  const float* x = (const float*)d_in[0];   // 512*64*121
  const float* w = (const float*)d_in[1];   // 64*64*512
  const float* Y = (const float*)d_in[2];   // 512*121
  float* out = (float*)d_out;               // 512*64*1771

  __hip_bfloat16* psi_t = (__hip_bfloat16*)d_ws;                       // 7744*64 bf16 (<1MB)
  __hip_bfloat16* x_t   = (__hip_bfloat16*)((char*)d_ws + (1 << 20));  // 61952*64 bf16 (~7.9MB)

  prep_kernel<<<576, 256, 0, stream>>>(x, w, Y, psi_t, x_t);
  conv_kernel_st<<<4229, 512, 0, stream>>>(psi_t, x_t, out);
  // ABLATION: store-less conv twice. T_nostore = (dur_r5 - dur_r3)/2.
  conv_kernel_ns<<<4229, 512, 0, stream>>>(psi_t, x_t, out);
  conv_kernel_ns<<<4229, 512, 0, stream>>>(psi_t, x_t, out);
}

// Round 6
// 337.777 us; speedup vs baseline: 1.5698x; 1.5122x over previous
//
#include <hip/hip_runtime.h>
#include <hip/hip_bf16.h>

// S2Conv: x (512,64,121) f32, w (64,64,512) f32, Y (512,121) f32
// out (512,64,1771) f32.
// psi[e,g,i] = sum_n Y[n,i] w[e,g,n] / sqrt(512)
// out[b,g, OFF_l + u*d + m] = (1/8) sum_e psi[e,g,l^2+u] * x[b,e,l^2+m]
//
// Round 6: conv read-path fix. R5 ablation: stores ~10us, loads ~76us of
// conv's 86us -> read-bound (4x redundant B-panel loads, 575 MB scattered).
// New conv: stage A(8KB)+B(32KB) panels ONCE per block into XOR-swizzled LDS
// (coalesced reg-staged), fragments from LDS, direct masked stores from acc
// (no LDS output staging). 40KB LDS -> 3 blocks/CU. Fragment data + MFMA
// order bit-identical to R3 -> absmax unchanged.

#define OUTROW 1771
#define OUTB   113344  // 64*1771

typedef __attribute__((ext_vector_type(8))) short bf16x8;
typedef __attribute__((ext_vector_type(4))) float floatx4;

// cumulative conv block counts per l (NGT*NBT)
__device__ __constant__ int c_blk[12] = {0,2,30,96,216,406,705,1137,1633,2403,3283,4229};
__device__ __constant__ signed char c_ltab[121] = {
  0,
  1,1,1,
  2,2,2,2,2,
  3,3,3,3,3,3,3,
  4,4,4,4,4,4,4,4,4,
  5,5,5,5,5,5,5,5,5,5,5,
  6,6,6,6,6,6,6,6,6,6,6,6,6,
  7,7,7,7,7,7,7,7,7,7,7,7,7,7,7,
  8,8,8,8,8,8,8,8,8,8,8,8,8,8,8,8,8,
  9,9,9,9,9,9,9,9,9,9,9,9,9,9,9,9,9,9,9,
  10,10,10,10,10,10,10,10,10,10,10,10,10,10,10,10,10,10,10,10,10
};

// ---------------------------------------------------------------------------
// Prep (unchanged): blocks [0,64): psi via MFMA, one block per g.
//                   blocks [64,576): x_t transpose, one block per b.
// psi_t[64*l^2 + g*d + u][e] = scale * sum_n w[e,g,n]*Y[n,l^2+u]   (bf16)
// x_t [512*l^2 + b*d + m][e] = x[b,e,l^2+m]                        (bf16)
// ---------------------------------------------------------------------------
__global__ __launch_bounds__(256) void prep_kernel(
    const float* __restrict__ x, const float* __restrict__ w,
    const float* __restrict__ Y,
    __hip_bfloat16* __restrict__ psi_t, __hip_bfloat16* __restrict__ x_t)
{
  __shared__ float smem[8256];
  const int t = threadIdx.x;

  if (blockIdx.x < 64) {
    const int g    = blockIdx.x;
    const int wv   = t >> 6, lane = t & 63;
    const int ln15 = lane & 15, quad = lane >> 4;

    floatx4 acc[2][4] = {};   // [i-tile][e-tile], statically indexed

    for (int n0 = 0; n0 < 512; n0 += 64) {
      __syncthreads();
      {
        const float4* src = (const float4*)(Y + n0*121);
        float4* dst = (float4*)smem;
        for (int idx = t; idx < 1936; idx += 256) dst[idx] = src[idx];
      }
      __syncthreads();

      #pragma unroll
      for (int ks = 0; ks < 2; ++ks) {
        const int kb = ks*32 + quad*8;

        bf16x8 ahi[2], alo[2];
        #pragma unroll
        for (int ti = 0; ti < 2; ++ti) {
          const int irow = (wv << 5) + (ti << 4) + ln15;
          #pragma unroll
          for (int j = 0; j < 8; ++j) {
            float v = smem[(kb + j)*121 + irow];
            __hip_bfloat16 h = __float2bfloat16(v);
            float hf = __bfloat162float(h);
            __hip_bfloat16 lo = __float2bfloat16(v - hf);
            ahi[ti][j] = *(short*)&h;
            alo[ti][j] = *(short*)&lo;
          }
        }

        bf16x8 bhi[4], blo[4];
        #pragma unroll
        for (int te = 0; te < 4; ++te) {
          const int e = (te << 4) + ln15;
          const float* wp = w + ((e << 6) + g)*512 + n0 + kb;
          float4 wa = *(const float4*)wp;
          float4 wb = *(const float4*)(wp + 4);
          float v[8] = {wa.x, wa.y, wa.z, wa.w, wb.x, wb.y, wb.z, wb.w};
          #pragma unroll
          for (int j = 0; j < 8; ++j) {
            __hip_bfloat16 h = __float2bfloat16(v[j]);
            float hf = __bfloat162float(h);
            __hip_bfloat16 lo = __float2bfloat16(v[j] - hf);
            bhi[te][j] = *(short*)&h;
            blo[te][j] = *(short*)&lo;
          }
        }

        #pragma unroll
        for (int ti = 0; ti < 2; ++ti) {
          #pragma unroll
          for (int te = 0; te < 4; ++te) {
            acc[ti][te] = __builtin_amdgcn_mfma_f32_16x16x32_bf16(ahi[ti], bhi[te], acc[ti][te], 0, 0, 0);
            acc[ti][te] = __builtin_amdgcn_mfma_f32_16x16x32_bf16(ahi[ti], blo[te], acc[ti][te], 0, 0, 0);
            acc[ti][te] = __builtin_amdgcn_mfma_f32_16x16x32_bf16(alo[ti], bhi[te], acc[ti][te], 0, 0, 0);
          }
        }
      }
    }

    const float scale = 0.00552427172801990267f;  // 1/(8*sqrt(512))
    #pragma unroll
    for (int ti = 0; ti < 2; ++ti) {
      #pragma unroll
      for (int rr = 0; rr < 4; ++rr) {
        const int i = (wv << 5) + (ti << 4) + (quad << 2) + rr;
        if (i < 121) {
          int l = c_ltab[i];
          int d = 2*l + 1;
          int row = 64*l*l + g*d + (i - l*l);
          #pragma unroll
          for (int te = 0; te < 4; ++te) {
            __hip_bfloat16 hv = __float2bfloat16(acc[ti][te][rr] * scale);
            psi_t[row*64 + (te << 4) + ln15] = hv;
          }
        }
      }
    }
  } else {
    const int b = blockIdx.x - 64;
    {
      const float4* src = (const float4*)(x + b*7744);
      float4* dst = (float4*)smem;
      for (int idx = t; idx < 1936; idx += 256) dst[idx] = src[idx];
    }
    __syncthreads();
    const int wv = t >> 6, lane = t & 63;
    for (int ii = wv; ii < 121; ii += 4) {
      int l = c_ltab[ii];
      int d = 2*l + 1;
      int row = 512*l*l + b*d + (ii - l*l);
      x_t[row*64 + lane] = __float2bfloat16(smem[lane*121 + ii]);
    }
  }
}

// ---------------------------------------------------------------------------
// Conv: per-l GEMM, (g,b)-aligned 64p x 256q tiles, K=64, 512 threads.
// A-panel (64 rows) + B-panel (256 rows) staged once per block into LDS with
// slot-XOR swizzle (slot ^= row&7 per 16B slot) -> bank-uniform ds_read_b128.
// Direct masked global stores from acc (no LDS output staging).
// ---------------------------------------------------------------------------
template <int L>
__device__ void conv_body(int r, int t,
                          const ushort* __restrict__ psi,
                          const ushort* __restrict__ xt,
                          float* __restrict__ out, ushort* sm)
{
  constexpr int d    = 2*L + 1;
  constexpr int GT   = 64  / d;            // whole g's per block
  constexpr int BT   = 256 / d;            // whole b's per block
  constexpr int NBT  = (512 + BT - 1) / BT;
  constexpr int OFFL = L*(2*L - 1)*(2*L + 1)/3;   // sum_{k<L} (2k+1)^2
  constexpr int PMAXR = 64*d  - 1;         // last valid psi row for this l
  constexpr int QMAXR = 512*d - 1;         // last valid x_t row for this l

  const int wv = t >> 6, lane = t & 63;
  const int wslot = wv & 3, qhalf = wv >> 2;
  const int ln15 = lane & 15, quad = lane >> 4;

  const int gtI = r / NBT;                 // compile-time magic div
  const int btI = r - gtI*NBT;
  const int g0 = gtI*GT, b0 = btI*BT;
  const int p0 = g0*d, q0 = b0*d;

  const ushort* psiSec = psi + 64*L*L*64;
  const ushort* xSec   = xt + 512*L*L*64;

  ushort* smA = sm;          // 64 rows  x 64 ushorts (8 KB), slot-swizzled
  ushort* smB = sm + 4096;   // 256 rows x 64 ushorts (32 KB), slot-swizzled

  // ---- stage A: 512 chunks of 16B, coalesced reads, swizzled LDS writes ----
  {
    const int row = t >> 3, slot = t & 7;
    int prow = p0 + row; if (prow > PMAXR) prow = PMAXR;   // edge clamp
    bf16x8 v = *(const bf16x8*)(psiSec + prow*64 + slot*8);
    *(bf16x8*)(smA + row*64 + (((slot ^ (row & 7))) << 3)) = v;
  }
  // ---- stage B: 2048 chunks of 16B ----
  #pragma unroll
  for (int cc = 0; cc < 4; ++cc) {
    const int c = cc*512 + t;
    const int row = c >> 3, slot = c & 7;
    int qrow = q0 + row; if (qrow > QMAXR) qrow = QMAXR;   // edge clamp
    bf16x8 v = *(const bf16x8*)(xSec + qrow*64 + slot*8);
    *(bf16x8*)(smB + row*64 + (((slot ^ (row & 7))) << 3)) = v;
  }
  __syncthreads();

  // A fragments from LDS (same data as R3's global af0/af1)
  const int ar = wslot*16 + ln15;
  const bf16x8 af0 = *(const bf16x8*)(smA + ar*64 + (((quad    ) ^ (ar & 7)) << 3));
  const bf16x8 af1 = *(const bf16x8*)(smA + ar*64 + (((quad + 4) ^ (ar & 7)) << 3));

  // per-lane output row offsets + masks for the 4 accumulator rows
  const int plim = (g0 + GT < 64 ? g0 + GT : 64) * d;
  const int qlim = (b0 + BT < 512 ? b0 + BT : 512) * d;
  int rowoff[4]; bool pok[4];
  #pragma unroll
  for (int rr = 0; rr < 4; ++rr) {
    const int p_abs = p0 + wslot*16 + quad*4 + rr;
    const int gg = p_abs / d;              // compile-time magic
    const int uu = p_abs - gg*d;
    rowoff[rr] = gg*OUTROW + uu*d;
    pok[rr] = p_abs < plim;
  }

  #pragma unroll
  for (int qi = 0; qi < 8; ++qi) {
    const int qq = qhalf*8 + qi;
    const int br = qq*16 + ln15;
    bf16x8 bf0 = *(const bf16x8*)(smB + br*64 + (((quad    ) ^ (br & 7)) << 3));
    bf16x8 bf1 = *(const bf16x8*)(smB + br*64 + (((quad + 4) ^ (br & 7)) << 3));
    floatx4 acc = {0.f, 0.f, 0.f, 0.f};
    acc = __builtin_amdgcn_mfma_f32_16x16x32_bf16(af0, bf0, acc, 0, 0, 0);
    acc = __builtin_amdgcn_mfma_f32_16x16x32_bf16(af1, bf1, acc, 0, 0, 0);
    const int q_abs = q0 + br;
    const int bb = q_abs / d;              // compile-time magic
    const int mm = q_abs - bb*d;
    const bool qok = q_abs < qlim;
    const int obase = bb*OUTB + OFFL + mm;
    #pragma unroll
    for (int rr = 0; rr < 4; ++rr)
      if (qok && pok[rr]) out[obase + rowoff[rr]] = acc[rr];
  }
}

__global__ __launch_bounds__(512) void conv_kernel(
    const __hip_bfloat16* __restrict__ psi_t,
    const __hip_bfloat16* __restrict__ x_t,
    float* __restrict__ out)
{
  __shared__ __align__(16) ushort sm[20480];  // 40 KB -> 3 blocks/CU (24 waves)

  // bijective XCD swizzle (NWG=4229 = 8*528+5)
  const int orig = blockIdx.x;
  const int xcd = orig & 7, idx = orig >> 3;
  const int bid = (xcd < 5 ? xcd*529 : 2645 + (xcd - 5)*528) + idx;

  int l = 0;
  #pragma unroll
  for (int ll = 1; ll <= 10; ++ll)
    if (bid >= c_blk[ll]) l = ll;
  const int r = bid - c_blk[l];

  const ushort* psi = (const ushort*)psi_t;
  const ushort* xt  = (const ushort*)x_t;
  const int t = threadIdx.x;

  switch (l) {
    case 0:  conv_body<0 >(r, t, psi, xt, out, sm); break;
    case 1:  conv_body<1 >(r, t, psi, xt, out, sm); break;
    case 2:  conv_body<2 >(r, t, psi, xt, out, sm); break;
    case 3:  conv_body<3 >(r, t, psi, xt, out, sm); break;
    case 4:  conv_body<4 >(r, t, psi, xt, out, sm); break;
    case 5:  conv_body<5 >(r, t, psi, xt, out, sm); break;
    case 6:  conv_body<6 >(r, t, psi, xt, out, sm); break;
    case 7:  conv_body<7 >(r, t, psi, xt, out, sm); break;
    case 8:  conv_body<8 >(r, t, psi, xt, out, sm); break;
    case 9:  conv_body<9 >(r, t, psi, xt, out, sm); break;
    default: conv_body<10>(r, t, psi, xt, out, sm); break;
  }
}

extern "C" void kernel_launch(void* const* d_in, const int* in_sizes, int n_in,
                              void* d_out, int out_size, void* d_ws, size_t ws_size,
                              hipStream_t stream) {
  const float* x = (const float*)d_in[0];   // 512*64*121
  const float* w = (const float*)d_in[1];   // 64*64*512
  const float* Y = (const float*)d_in[2];   // 512*121
  float* out = (float*)d_out;               // 512*64*1771

  __hip_bfloat16* psi_t = (__hip_bfloat16*)d_ws;                       // 7744*64 bf16 (<1MB)
  __hip_bfloat16* x_t   = (__hip_bfloat16*)((char*)d_ws + (1 << 20));  // 61952*64 bf16 (~7.9MB)

  prep_kernel<<<576, 256, 0, stream>>>(x, w, Y, psi_t, x_t);
  conv_kernel<<<4229, 512, 0, stream>>>(psi_t, x_t, out);
}